// Round 4
// baseline (97.630 us; speedup 1.0000x reference)
//
#include <hip/hip_runtime.h>
#include <math.h>

#define N_TOK 2048          // tokens per modality (64*32)
#define NMOD  3
#define NTOT  6144          // N_TOK * NMOD
#define D     256
#define INV_TAU 10.0f

#define BM 128              // output tile (rows == cols)
#define NBLK (NTOT / BM)    // 48

typedef float  f32x4  __attribute__((ext_vector_type(4)));
typedef short  bf16x8 __attribute__((ext_vector_type(8)));

// ------------------------------------------------------------- helpers
__device__ __forceinline__ unsigned short f2bf(float x) {
    unsigned int u = __float_as_uint(x);
    unsigned int r = (u + 0x7fffu + ((u >> 16) & 1u)) >> 16;   // RNE
    return (unsigned short)r;
}

// ------------------------------------------------------------- normalize + bf16
__global__ void norm_kernel(const float* __restrict__ a,
                            const float* __restrict__ b,
                            const float* __restrict__ c,
                            unsigned short* __restrict__ H) {
    int row = blockIdx.x;
    const float* src;
    if (row < N_TOK)            src = a + (size_t)row * D;
    else if (row < 2 * N_TOK)   src = b + (size_t)(row - N_TOK) * D;
    else                        src = c + (size_t)(row - 2 * N_TOK) * D;

    int t = threadIdx.x;                 // 256 threads, one element each
    float v = src[t];
    float ss = v * v;
    #pragma unroll
    for (int o = 32; o > 0; o >>= 1) ss += __shfl_down(ss, o, 64);
    __shared__ float red[4];
    int lane = t & 63, w = t >> 6;
    if (lane == 0) red[w] = ss;
    __syncthreads();
    float tot = red[0] + red[1] + red[2] + red[3];
    float inv = rsqrtf(fmaxf(tot, 1e-16f));
    H[(size_t)row * D + t] = f2bf(v * inv);
}

// ------------------------------------------------------------- LDS-free bf16 MFMA GEMM
// C = F F^T. F (3 MB bf16) is L2-resident; MFMA fragments are loaded straight
// from global (lane pattern: row = lane&15 within frag, 16B of k per lane;
// lanes {x, x+16, x+32, x+48} cover one row's contiguous 64 B -> full-line L2
// reads). No LDS, no barriers in the k-loop. Fused exp-rowsum epilogue.
__global__ __launch_bounds__(256)
void gemm_bf16(const unsigned short* __restrict__ H,
               float* __restrict__ C,
               float* __restrict__ partials) {
    const int bc = blockIdx.x, br = blockIdx.y;

    const int t    = threadIdx.x;
    const int lane = t & 63;
    const int w    = t >> 6;      // wave id 0..3
    const int wm   = w >> 1;      // 0..1
    const int wn   = w & 1;       // 0..1

    f32x4 acc[4][4] = {};

    // per-lane fragment base addresses (k advances by immediate offsets)
    const unsigned short* Arow =
        H + (size_t)(br * BM + wm * 64 + (lane & 15)) * D + (lane >> 4) * 8;
    const unsigned short* Brow =
        H + (size_t)(bc * BM + wn * 64 + (lane & 15)) * D + (lane >> 4) * 8;

    #pragma unroll
    for (int kh = 0; kh < 8; ++kh) {            // 8 k-steps of 32
        bf16x8 a[4], b[4];
        #pragma unroll
        for (int m = 0; m < 4; ++m)
            a[m] = *(const bf16x8*)(Arow + (size_t)m * 16 * D + kh * 32);
        #pragma unroll
        for (int n = 0; n < 4; ++n)
            b[n] = *(const bf16x8*)(Brow + (size_t)n * 16 * D + kh * 32);
        #pragma unroll
        for (int m = 0; m < 4; ++m)
            #pragma unroll
            for (int n = 0; n < 4; ++n)
                acc[m][n] = __builtin_amdgcn_mfma_f32_16x16x32_bf16(
                    a[m], b[n], acc[m][n], 0, 0, 0);
    }

    // ---- epilogue: store C + per-row exp sums
    __shared__ float rowsum[BM][2];
    const int gr0 = br * BM, gc0 = bc * BM;
    float rs[4][4];
    #pragma unroll
    for (int m = 0; m < 4; ++m)
        #pragma unroll
        for (int j = 0; j < 4; ++j) rs[m][j] = 0.0f;

    #pragma unroll
    for (int m = 0; m < 4; ++m) {
        #pragma unroll
        for (int n = 0; n < 4; ++n) {
            #pragma unroll
            for (int j = 0; j < 4; ++j) {
                int rl = wm * 64 + m * 16 + (lane >> 4) * 4 + j;
                int cl = wn * 64 + n * 16 + (lane & 15);
                float v = acc[m][n][j];
                C[(size_t)(gr0 + rl) * NTOT + gc0 + cl] = v;
                float e = __expf(v * INV_TAU);
                if (gr0 + rl == gc0 + cl) e = 0.0f;   // mask diagonal
                rs[m][j] += e;
            }
        }
    }
    // reduce across the 16 lanes sharing a row (lane bits 0..3)
    #pragma unroll
    for (int m = 0; m < 4; ++m)
        #pragma unroll
        for (int j = 0; j < 4; ++j) {
            float s = rs[m][j];
            s += __shfl_xor(s, 1, 64);
            s += __shfl_xor(s, 2, 64);
            s += __shfl_xor(s, 4, 64);
            s += __shfl_xor(s, 8, 64);
            rs[m][j] = s;
        }
    if ((lane & 15) == 0) {
        #pragma unroll
        for (int m = 0; m < 4; ++m)
            #pragma unroll
            for (int j = 0; j < 4; ++j)
                rowsum[wm * 64 + m * 16 + (lane >> 4) * 4 + j][wn] = rs[m][j];
    }
    __syncthreads();
    if (t < BM)
        partials[(size_t)bc * NTOT + gr0 + t] = rowsum[t][0] + rowsum[t][1];
}

// ------------------------------------------------------------- combine per-row
__global__ void loss_combine(const float* __restrict__ C,
                             const float* __restrict__ partials,
                             float* __restrict__ blocksum) {
    int r = blockIdx.x * 256 + threadIdx.x;   // 24 blocks x 256
    float s = 0.0f;
    #pragma unroll 8
    for (int b = 0; b < NBLK; ++b) s += partials[(size_t)b * NTOT + r];

    int k = r >> 11;          // r / 2048
    int i = r & 2047;
    float ps = 0.0f;
    #pragma unroll
    for (int j = 0; j < NMOD; ++j)
        if (j != k) ps += __expf(INV_TAU * C[(size_t)r * NTOT + i + j * N_TOK]);

    float rl = __logf(s) - __logf(ps);

    #pragma unroll
    for (int o = 32; o > 0; o >>= 1) rl += __shfl_down(rl, o, 64);
    __shared__ float red[4];
    int lane = threadIdx.x & 63, w = threadIdx.x >> 6;
    if (lane == 0) red[w] = rl;
    __syncthreads();
    if (threadIdx.x == 0)
        blocksum[blockIdx.x] = red[0] + red[1] + red[2] + red[3];
}

__global__ void final_sum(const float* __restrict__ blocksum, float* __restrict__ out) {
    int t = threadIdx.x;   // 64 threads
    float s = (t < 24) ? blocksum[t] : 0.0f;
    #pragma unroll
    for (int o = 32; o > 0; o >>= 1) s += __shfl_down(s, o, 64);
    if (t == 0) out[0] = s / (float)NTOT;
}

// ------------------------------------------------------------- launch
extern "C" void kernel_launch(void* const* d_in, const int* in_sizes, int n_in,
                              void* d_out, int out_size, void* d_ws, size_t ws_size,
                              hipStream_t stream) {
    const float* aerial = (const float*)d_in[0];
    const float* s2     = (const float*)d_in[1];
    const float* s1     = (const float*)d_in[2];
    float* out = (float*)d_out;

    unsigned short* H   = (unsigned short*)d_ws;                 // 6144*256 bf16 = 3 MB
    float* partials     = (float*)((char*)d_ws + (size_t)NTOT * D * 2);  // [48][6144] f32
    float* blocksum     = partials + (size_t)NBLK * NTOT;        // 24 floats
    float* C            = out + 1;                               // logits 6144x6144

    norm_kernel<<<NTOT, 256, 0, stream>>>(aerial, s2, s1, H);

    dim3 grid(NBLK, NBLK);
    gemm_bf16<<<grid, 256, 0, stream>>>(H, C, partials);

    loss_combine<<<NTOT / 256, 256, 0, stream>>>(C, partials, blocksum);
    final_sum<<<1, 64, 0, stream>>>(blocksum, out);
}

// Round 5
// 73.430 us; speedup vs baseline: 1.3296x; 1.3296x over previous
//
#include <hip/hip_runtime.h>
#include <math.h>

#define N_TOK 2048          // tokens per modality (64*32)
#define NMOD  3
#define NTOT  6144          // N_TOK * NMOD
#define D     256
#define INV_TAU 10.0f

#define BM2 256             // block tile (rows == cols)
#define BKS 32              // k-step
#define NB2 (NTOT / BM2)    // 24
#define KSTEPS (D / BKS)    // 8

typedef float  f32x4  __attribute__((ext_vector_type(4)));
typedef short  bf16x8 __attribute__((ext_vector_type(8)));

// ------------------------------------------------------------- helpers
__device__ __forceinline__ unsigned short f2bf(float x) {
    unsigned int u = __float_as_uint(x);
    unsigned int r = (u + 0x7fffu + ((u >> 16) & 1u)) >> 16;   // RNE
    return (unsigned short)r;
}

__device__ __forceinline__ void gload16(const void* g, void* s) {
    __builtin_amdgcn_global_load_lds(
        (const __attribute__((address_space(1))) void*)g,
        (__attribute__((address_space(3))) void*)s, 16, 0, 0);
}

// ------------------------------------------------------------- normalize + bf16
__global__ void norm_kernel(const float* __restrict__ a,
                            const float* __restrict__ b,
                            const float* __restrict__ c,
                            unsigned short* __restrict__ H) {
    int row = blockIdx.x;
    const float* src;
    if (row < N_TOK)            src = a + (size_t)row * D;
    else if (row < 2 * N_TOK)   src = b + (size_t)(row - N_TOK) * D;
    else                        src = c + (size_t)(row - 2 * N_TOK) * D;

    int t = threadIdx.x;                 // 256 threads, one element each
    float v = src[t];
    float ss = v * v;
    #pragma unroll
    for (int o = 32; o > 0; o >>= 1) ss += __shfl_down(ss, o, 64);
    __shared__ float red[4];
    int lane = t & 63, w = t >> 6;
    if (lane == 0) red[w] = ss;
    __syncthreads();
    float tot = red[0] + red[1] + red[2] + red[3];
    float inv = rsqrtf(fmaxf(tot, 1e-16f));
    H[(size_t)row * D + t] = f2bf(v * inv);
}

// ------------------------------------------------------------- 256x256 pipelined MFMA GEMM
// C = F F^T. 8 waves (wm 0..1 x wn 0..3); per-wave 128x64 sub-tile
// (8 m-frags x 4 n-frags of mfma_f32_16x16x32_bf16). Double-buffered LDS,
// next k-step staged at loop top (latency hides under MFMA), one barrier/step.
// Epilogue uses symmetry: frag (rl, cl) stored at C[gc0+cl][gr0+rl] where the
// lane's 4 acc elements are memory-consecutive -> dword+float2+dword stores.
// Fused exp-rowsum: block (br,bc) emits partials[br][gc0+cl].
__global__ __launch_bounds__(512, 2)
void gemm_bf16_big(const unsigned short* __restrict__ H,
                   float* __restrict__ C,
                   float* __restrict__ partials) {
    const int bc = blockIdx.x, br = blockIdx.y;

    __shared__ unsigned short As[2][BM2 * BKS];   // 2 x 16 KB
    __shared__ unsigned short Bs[2][BM2 * BKS];   // 2 x 16 KB  (total 64 KB)

    const int t    = threadIdx.x;
    const int lane = t & 63;
    const int w    = t >> 6;      // wave id 0..7
    const int wm   = w >> 2;      // 0..1  (row half, 128)
    const int wn   = w & 3;       // 0..3  (col quarter, 64)

    f32x4 acc[8][4] = {};

    const unsigned short* Ab = H + (size_t)(br * BM2) * D;
    const unsigned short* Bb = H + (size_t)(bc * BM2) * D;

    // prologue: stage step 0
    #pragma unroll
    for (int c = 0; c < 2; ++c) {
        int gbase = c * 512 + w * 64;           // wave-uniform
        int g     = gbase + lane;
        int row   = g >> 2;
        int slot  = (g & 3) ^ (row & 3);        // involution (pre-swizzled source)
        gload16(Ab + (size_t)row * D + slot * 8, (unsigned short*)As[0] + gbase * 8);
        gload16(Bb + (size_t)row * D + slot * 8, (unsigned short*)Bs[0] + gbase * 8);
    }
    __syncthreads();

    for (int ks = 0; ks < KSTEPS; ++ks) {
        const int buf = ks & 1;
        // stage next step into the other buffer (issued early, drains at barrier)
        if (ks < KSTEPS - 1) {
            const int kk = (ks + 1) * BKS;
            #pragma unroll
            for (int c = 0; c < 2; ++c) {
                int gbase = c * 512 + w * 64;
                int g     = gbase + lane;
                int row   = g >> 2;
                int slot  = (g & 3) ^ (row & 3);
                gload16(Ab + (size_t)row * D + kk + slot * 8,
                        (unsigned short*)As[buf ^ 1] + gbase * 8);
                gload16(Bb + (size_t)row * D + kk + slot * 8,
                        (unsigned short*)Bs[buf ^ 1] + gbase * 8);
            }
        }
        // fragments from current buffer (rows at 64 B stride, slot-swizzled)
        bf16x8 a[8], b[4];
        #pragma unroll
        for (int m = 0; m < 8; ++m) {
            int r    = wm * 128 + m * 16 + (lane & 15);
            int slot = (lane >> 4) ^ (r & 3);
            a[m] = *(const bf16x8*)&As[buf][r * 32 + slot * 8];
        }
        #pragma unroll
        for (int n = 0; n < 4; ++n) {
            int r    = wn * 64 + n * 16 + (lane & 15);
            int slot = (lane >> 4) ^ (r & 3);
            b[n] = *(const bf16x8*)&Bs[buf][r * 32 + slot * 8];
        }
        __builtin_amdgcn_s_setprio(1);
        #pragma unroll
        for (int m = 0; m < 8; ++m)
            #pragma unroll
            for (int n = 0; n < 4; ++n)
                acc[m][n] = __builtin_amdgcn_mfma_f32_16x16x32_bf16(
                    a[m], b[n], acc[m][n], 0, 0, 0);
        __builtin_amdgcn_s_setprio(0);
        __syncthreads();
    }

    // ---- epilogue: transposed store + fused exp row-sums
    const int gr0 = br * BM2, gc0 = bc * BM2;
    float rs[4] = {0.0f, 0.0f, 0.0f, 0.0f};

    #pragma unroll
    for (int n = 0; n < 4; ++n) {
        int cl = wn * 64 + n * 16 + (lane & 15);            // output row (transposed)
        float* prow = C + (size_t)(gc0 + cl) * NTOT + gr0;
        #pragma unroll
        for (int m = 0; m < 8; ++m) {
            int col0 = wm * 128 + m * 16 + (lane >> 4) * 4; // output col base
            f32x4 v = acc[m][n];
            float* p = prow + col0;
            p[0] = v[0];
            *reinterpret_cast<float2*>(p + 1) = make_float2(v[1], v[2]);  // 8B-aligned
            p[3] = v[3];
            #pragma unroll
            for (int j = 0; j < 4; ++j) {
                float e = __expf(v[j] * INV_TAU);
                if (gr0 + col0 + j == gc0 + cl) e = 0.0f;   // mask diagonal
                rs[n] += e;
            }
        }
    }

    // rowsum aliased onto dead staging LDS (free after last k-step barrier)
    float (*rowsum)[2] = (float(*)[2])&As[0][0];            // [256][2] = 2 KB
    #pragma unroll
    for (int n = 0; n < 4; ++n) {
        float s = rs[n];
        s += __shfl_xor(s, 16, 64);
        s += __shfl_xor(s, 32, 64);
        if (lane < 16)
            rowsum[wn * 64 + n * 16 + lane][wm] = s;
    }
    __syncthreads();
    if (t < BM2)
        partials[(size_t)br * NTOT + gc0 + t] = rowsum[t][0] + rowsum[t][1];
}

// ------------------------------------------------------------- combine per-row
__global__ void loss_combine(const float* __restrict__ C,
                             const float* __restrict__ partials,
                             float* __restrict__ blocksum) {
    int r = blockIdx.x * 256 + threadIdx.x;   // 24 blocks x 256
    float s = 0.0f;
    #pragma unroll
    for (int b = 0; b < NB2; ++b) s += partials[(size_t)b * NTOT + r];

    int k = r >> 11;          // r / 2048
    int i = r & 2047;
    float ps = 0.0f;
    #pragma unroll
    for (int j = 0; j < NMOD; ++j)
        if (j != k) ps += __expf(INV_TAU * C[(size_t)r * NTOT + i + j * N_TOK]);

    float rl = __logf(s) - __logf(ps);

    #pragma unroll
    for (int o = 32; o > 0; o >>= 1) rl += __shfl_down(rl, o, 64);
    __shared__ float red[4];
    int lane = threadIdx.x & 63, w = threadIdx.x >> 6;
    if (lane == 0) red[w] = rl;
    __syncthreads();
    if (threadIdx.x == 0)
        blocksum[blockIdx.x] = red[0] + red[1] + red[2] + red[3];
}

__global__ void final_sum(const float* __restrict__ blocksum, float* __restrict__ out) {
    int t = threadIdx.x;   // 64 threads
    float s = (t < 24) ? blocksum[t] : 0.0f;
    #pragma unroll
    for (int o = 32; o > 0; o >>= 1) s += __shfl_down(s, o, 64);
    if (t == 0) out[0] = s / (float)NTOT;
}

// ------------------------------------------------------------- launch
extern "C" void kernel_launch(void* const* d_in, const int* in_sizes, int n_in,
                              void* d_out, int out_size, void* d_ws, size_t ws_size,
                              hipStream_t stream) {
    const float* aerial = (const float*)d_in[0];
    const float* s2     = (const float*)d_in[1];
    const float* s1     = (const float*)d_in[2];
    float* out = (float*)d_out;

    unsigned short* H   = (unsigned short*)d_ws;                 // 6144*256 bf16 = 3 MB
    float* partials     = (float*)((char*)d_ws + (size_t)NTOT * D * 2);  // [24][6144] f32
    float* blocksum     = partials + (size_t)NB2 * NTOT;         // 24 floats
    float* C            = out + 1;                               // logits 6144x6144

    norm_kernel<<<NTOT, 256, 0, stream>>>(aerial, s2, s1, H);

    dim3 grid(NB2, NB2);                                         // 24x24
    gemm_bf16_big<<<grid, 512, 0, stream>>>(H, C, partials);

    loss_combine<<<NTOT / 256, 256, 0, stream>>>(C, partials, blocksum);
    final_sum<<<1, 64, 0, stream>>>(blocksum, out);
}

// Round 6
// 69.302 us; speedup vs baseline: 1.4088x; 1.0596x over previous
//
#include <hip/hip_runtime.h>
#include <math.h>

#define N_TOK 2048          // tokens per modality (64*32)
#define NMOD  3
#define NTOT  6144          // N_TOK * NMOD
#define D     256
#define INV_TAU 10.0f

#define BM 128              // output tile (rows == cols)
#define BK 64               // k-step
#define NBLK (NTOT / BM)    // 48
#define LP 132              // padded bounce-row stride (words); 132*4=528 ≡ 16 mod 32 banks

typedef float  f32x4  __attribute__((ext_vector_type(4)));
typedef short  bf16x8 __attribute__((ext_vector_type(8)));

// ------------------------------------------------------------- helpers
__device__ __forceinline__ unsigned short f2bf(float x) {
    unsigned int u = __float_as_uint(x);
    unsigned int r = (u + 0x7fffu + ((u >> 16) & 1u)) >> 16;   // RNE
    return (unsigned short)r;
}

__device__ __forceinline__ void gload16(const void* g, void* s) {
    __builtin_amdgcn_global_load_lds(
        (const __attribute__((address_space(1))) void*)g,
        (__attribute__((address_space(3))) void*)s, 16, 0, 0);
}

// ------------------------------------------------------------- normalize + bf16
__global__ void norm_kernel(const float* __restrict__ a,
                            const float* __restrict__ b,
                            const float* __restrict__ c,
                            unsigned short* __restrict__ H) {
    int row = blockIdx.x;
    const float* src;
    if (row < N_TOK)            src = a + (size_t)row * D;
    else if (row < 2 * N_TOK)   src = b + (size_t)(row - N_TOK) * D;
    else                        src = c + (size_t)(row - 2 * N_TOK) * D;

    int t = threadIdx.x;                 // 256 threads, one element each
    float v = src[t];
    float ss = v * v;
    #pragma unroll
    for (int o = 32; o > 0; o >>= 1) ss += __shfl_down(ss, o, 64);
    __shared__ float red[4];
    int lane = t & 63, w = t >> 6;
    if (lane == 0) red[w] = ss;
    __syncthreads();
    float tot = red[0] + red[1] + red[2] + red[3];
    float inv = rsqrtf(fmaxf(tot, 1e-16f));
    H[(size_t)row * D + t] = f2bf(v * inv);
}

// ------------------------------------------------------------- bf16 MFMA GEMM, coalesced-store epilogue
// C = F F^T. 128x128 tile, 4 waves of 64x64 (round-2 verified k-loop).
// Epilogue: exp-rowsum from regs, then C tile bounced through LDS
// ([64][132] f32) and stored as coalesced float4 runs (misalign-by-1 aware).
__global__ __launch_bounds__(256)
void gemm_bf16(const unsigned short* __restrict__ H,
               float* __restrict__ C,
               float* __restrict__ partials) {
    const int bc = blockIdx.x, br = blockIdx.y;

    __shared__ __align__(16) unsigned char smem[64 * LP * 4];  // 33792 B (staging alias)
    unsigned short* As = (unsigned short*)smem;                 // 16 KB
    unsigned short* Bs = As + BM * BK;                          // 16 KB
    float* ldsf = (float*)smem;                                 // bounce view
    __shared__ float rowsum[BM][2];

    const int t    = threadIdx.x;
    const int lane = t & 63;
    const int w    = t >> 6;      // wave id 0..3
    const int wm   = w >> 1;      // 0..1
    const int wn   = w & 1;       // 0..1

    f32x4 acc[4][4] = {};

    const unsigned short* Abase = H + (size_t)(br * BM) * D;
    const unsigned short* Bbase = H + (size_t)(bc * BM) * D;

    for (int kk = 0; kk < D; kk += BK) {
        // ---- stage A,B tiles: linear LDS dest, inverse-swizzled global src
        #pragma unroll
        for (int i4 = 0; i4 < 4; ++i4) {
            int ch   = w * 4 + i4;                // 0..15 (1 KB chunks)
            int row  = ch * 8 + (lane >> 3);      // 0..127
            int slot = (lane & 7) ^ (row & 7);    // involution
            gload16(Abase + (size_t)row * D + kk + slot * 8,
                    (unsigned short*)As + ch * 512);
            gload16(Bbase + (size_t)row * D + kk + slot * 8,
                    (unsigned short*)Bs + ch * 512);
        }
        __syncthreads();

        // ---- compute: 2 k-halves of 32
        #pragma unroll
        for (int kh = 0; kh < 2; ++kh) {
            bf16x8 a[4], b[4];
            #pragma unroll
            for (int m = 0; m < 4; ++m) {
                int row  = wm * 64 + m * 16 + (lane & 15);
                int slot = (kh * 4 + (lane >> 4)) ^ (row & 7);
                a[m] = *(const bf16x8*)&As[row * 64 + slot * 8];
            }
            #pragma unroll
            for (int n = 0; n < 4; ++n) {
                int row  = wn * 64 + n * 16 + (lane & 15);
                int slot = (kh * 4 + (lane >> 4)) ^ (row & 7);
                b[n] = *(const bf16x8*)&Bs[row * 64 + slot * 8];
            }
            __builtin_amdgcn_s_setprio(1);
            #pragma unroll
            for (int m = 0; m < 4; ++m)
                #pragma unroll
                for (int n = 0; n < 4; ++n)
                    acc[m][n] = __builtin_amdgcn_mfma_f32_16x16x32_bf16(
                        a[m], b[n], acc[m][n], 0, 0, 0);
            __builtin_amdgcn_s_setprio(0);
        }
        __syncthreads();
    }

    // ---- exp row-sums from registers (round-2 verified)
    const int gr0 = br * BM, gc0 = bc * BM;
    float rs[4][4];
    #pragma unroll
    for (int m = 0; m < 4; ++m)
        #pragma unroll
        for (int j = 0; j < 4; ++j) rs[m][j] = 0.0f;

    #pragma unroll
    for (int m = 0; m < 4; ++m)
        #pragma unroll
        for (int n = 0; n < 4; ++n)
            #pragma unroll
            for (int j = 0; j < 4; ++j) {
                int rl = wm * 64 + m * 16 + (lane >> 4) * 4 + j;
                int cl = wn * 64 + n * 16 + (lane & 15);
                float e = __expf(acc[m][n][j] * INV_TAU);
                if (gr0 + rl == gc0 + cl) e = 0.0f;   // mask diagonal
                rs[m][j] += e;
            }
    #pragma unroll
    for (int m = 0; m < 4; ++m)
        #pragma unroll
        for (int j = 0; j < 4; ++j) {
            float s = rs[m][j];
            s += __shfl_xor(s, 1, 64);
            s += __shfl_xor(s, 2, 64);
            s += __shfl_xor(s, 4, 64);
            s += __shfl_xor(s, 8, 64);
            rs[m][j] = s;
        }
    if ((lane & 15) == 0) {
        #pragma unroll
        for (int m = 0; m < 4; ++m)
            #pragma unroll
            for (int j = 0; j < 4; ++j)
                rowsum[wm * 64 + m * 16 + (lane >> 4) * 4 + j][wn] = rs[m][j];
    }

    // ---- LDS-bounce coalesced store, two passes of 64 rows
    #pragma unroll
    for (int p = 0; p < 2; ++p) {
        __syncthreads();                       // staging dead / prev-pass reads done
        if (wm == p) {
            #pragma unroll
            for (int m = 0; m < 4; ++m)
                #pragma unroll
                for (int n = 0; n < 4; ++n)
                    #pragma unroll
                    for (int j = 0; j < 4; ++j) {
                        int rloc = m * 16 + (lane >> 4) * 4 + j;      // 0..63
                        int col  = wn * 64 + n * 16 + (lane & 15);    // 0..127
                        ldsf[rloc * LP + col] = acc[m][n][j];
                    }
        }
        __syncthreads();
        const int q = t & 31;                  // 32 threads per row
        #pragma unroll
        for (int it = 0; it < 8; ++it) {
            int r = (t >> 5) + it * 8;         // 0..63
            float* dst = C + (size_t)(gr0 + p * 64 + r) * NTOT + gc0;
            if (q < 31) {
                // float4 at col 3+4q: dword idx 1 + row*6144 + gc0 + 3+4q ≡ 0 mod 4
                f32x4 v = *(const f32x4*)&ldsf[r * LP + 3 + q * 4];
                *reinterpret_cast<f32x4*>(dst + 3 + q * 4) = v;
            } else {
                f32x4 e = *(const f32x4*)&ldsf[r * LP];   // cols 0..3 (16B-aligned LDS)
                dst[0] = e[0];
                *reinterpret_cast<float2*>(dst + 1) = make_float2(e[1], e[2]); // 8B-aligned
                dst[127] = ldsf[r * LP + 127];
            }
        }
    }

    __syncthreads();
    if (t < BM)
        partials[(size_t)bc * NTOT + gr0 + t] = rowsum[t][0] + rowsum[t][1];
}

// ------------------------------------------------------------- combine per-row
__global__ void loss_combine(const float* __restrict__ C,
                             const float* __restrict__ partials,
                             float* __restrict__ blocksum) {
    int r = blockIdx.x * 256 + threadIdx.x;   // 24 blocks x 256
    float s = 0.0f;
    #pragma unroll 8
    for (int b = 0; b < NBLK; ++b) s += partials[(size_t)b * NTOT + r];

    int k = r >> 11;          // r / 2048
    int i = r & 2047;
    float ps = 0.0f;
    #pragma unroll
    for (int j = 0; j < NMOD; ++j)
        if (j != k) ps += __expf(INV_TAU * C[(size_t)r * NTOT + i + j * N_TOK]);

    float rl = __logf(s) - __logf(ps);

    #pragma unroll
    for (int o = 32; o > 0; o >>= 1) rl += __shfl_down(rl, o, 64);
    __shared__ float red[4];
    int lane = threadIdx.x & 63, w = threadIdx.x >> 6;
    if (lane == 0) red[w] = rl;
    __syncthreads();
    if (threadIdx.x == 0)
        blocksum[blockIdx.x] = red[0] + red[1] + red[2] + red[3];
}

__global__ void final_sum(const float* __restrict__ blocksum, float* __restrict__ out) {
    int t = threadIdx.x;   // 64 threads
    float s = (t < 24) ? blocksum[t] : 0.0f;
    #pragma unroll
    for (int o = 32; o > 0; o >>= 1) s += __shfl_down(s, o, 64);
    if (t == 0) out[0] = s / (float)NTOT;
}

// ------------------------------------------------------------- launch
extern "C" void kernel_launch(void* const* d_in, const int* in_sizes, int n_in,
                              void* d_out, int out_size, void* d_ws, size_t ws_size,
                              hipStream_t stream) {
    const float* aerial = (const float*)d_in[0];
    const float* s2     = (const float*)d_in[1];
    const float* s1     = (const float*)d_in[2];
    float* out = (float*)d_out;

    unsigned short* H   = (unsigned short*)d_ws;                 // 6144*256 bf16 = 3 MB
    float* partials     = (float*)((char*)d_ws + (size_t)NTOT * D * 2);  // [48][6144] f32
    float* blocksum     = partials + (size_t)NBLK * NTOT;        // 24 floats
    float* C            = out + 1;                               // logits 6144x6144

    norm_kernel<<<NTOT, 256, 0, stream>>>(aerial, s2, s1, H);

    dim3 grid(NBLK, NBLK);
    gemm_bf16<<<grid, 256, 0, stream>>>(H, C, partials);

    loss_combine<<<NTOT / 256, 256, 0, stream>>>(C, partials, blocksum);
    final_sum<<<1, 64, 0, stream>>>(blocksum, out);
}